// Round 1
// baseline (299.722 us; speedup 1.0000x reference)
//
#include <hip/hip_runtime.h>
#include <hip/hip_bf16.h>

// Word embedding gather: out[t, :] = weight[ids[t], :]
// weight: [50257, 1024] fp32, ids: [16*2048] int32, out: [32768, 1024] fp32.
// Memory-bound; one block per token, each thread moves one float4.

#define DIM 1024

__global__ __launch_bounds__(256) void WordEmbedding_kernel(
    const float* __restrict__ weight,
    const int* __restrict__ ids,
    float* __restrict__ out) {
    const int token = blockIdx.x;
    const int idx = ids[token];
    const float4* __restrict__ src =
        (const float4*)(weight + (size_t)idx * DIM);
    float4* __restrict__ dst = (float4*)(out + (size_t)token * DIM);
    dst[threadIdx.x] = src[threadIdx.x];
}

extern "C" void kernel_launch(void* const* d_in, const int* in_sizes, int n_in,
                              void* d_out, int out_size, void* d_ws, size_t ws_size,
                              hipStream_t stream) {
    const float* weight = (const float*)d_in[0];
    const int* ids = (const int*)d_in[1];
    float* out = (float*)d_out;
    const int n_tokens = in_sizes[1];  // 16 * 2048 = 32768
    // DIM floats per row = DIM/4 float4 = 256 threads per block
    WordEmbedding_kernel<<<n_tokens, DIM / 4, 0, stream>>>(weight, ids, out);
}